// Round 1
// baseline (561.533 us; speedup 1.0000x reference)
//
#include <hip/hip_runtime.h>
#include <hip/hip_bf16.h>

using bf16 = __hip_bfloat16;
typedef __attribute__((ext_vector_type(8))) short short8;   // 8 x bf16 fragment (4 VGPRs)
typedef __attribute__((ext_vector_type(4))) float f32x4;

static constexpr int SEQ  = 2048;
static constexpr int HID  = 3072;
static constexpr int NH   = 24;
static constexpr int HD   = 128;
static constexpr int QKVN = 9216;

__device__ __forceinline__ f32x4 mfma_16x16x32(short8 a, short8 b, f32x4 c) {
  return __builtin_amdgcn_mfma_f32_16x16x32_bf16(a, b, c, 0, 0, 0);
}

#define GLOAD_LDS16(g, l) __builtin_amdgcn_global_load_lds(                 \
    (const __attribute__((address_space(1))) void*)(g),                    \
    (__attribute__((address_space(3))) void*)(l), 16, 0, 0)

// ---------------- fp32 -> bf16 vectorized convert ----------------
__global__ __launch_bounds__(256)
void cvt_f32_bf16_vec(const float* __restrict__ src, bf16* __restrict__ dst, int n4) {
  int i = blockIdx.x * 256 + threadIdx.x;
  if (i >= n4) return;
  float4 v = ((const float4*)src)[i];
  ushort4 o;
  bf16 t0 = __float2bfloat16(v.x); o.x = *(unsigned short*)&t0;
  bf16 t1 = __float2bfloat16(v.y); o.y = *(unsigned short*)&t1;
  bf16 t2 = __float2bfloat16(v.z); o.z = *(unsigned short*)&t2;
  bf16 t3 = __float2bfloat16(v.w); o.w = *(unsigned short*)&t3;
  ((ushort4*)dst)[i] = o;
}

// ---------------- fp32 (R x C) -> bf16 transposed (C x R) ----------------
__global__ __launch_bounds__(256)
void transpose_cvt(const float* __restrict__ src, bf16* __restrict__ dst, int R, int C) {
  __shared__ float tile[32][33];
  const int c0 = blockIdx.x * 32, r0 = blockIdx.y * 32;
  const int tc = threadIdx.x & 31, tr = threadIdx.x >> 5;
  #pragma unroll
  for (int i = 0; i < 4; ++i)
    tile[tr + i * 8][tc] = src[(long)(r0 + tr + i * 8) * C + c0 + tc];
  __syncthreads();
  #pragma unroll
  for (int i = 0; i < 4; ++i)
    dst[(long)(c0 + tr + i * 8) * R + r0 + tc] = __float2bfloat16(tile[tc][tr + i * 8]);
}

// ---------------- GEMM: C[M,N] = A[M,K] * BT[N,K]^T (+bias), m97 structure ----------------
template<int BIAS, int OUTF32>
__global__ __launch_bounds__(256, 2)
void gemm_bt(const bf16* __restrict__ A, const bf16* __restrict__ BT,
             const float* __restrict__ bias, void* __restrict__ Cout,
             int M, int N, int K) {
  __shared__ __align__(16) bf16 As[128 * 64];
  __shared__ __align__(16) bf16 Bs[128 * 64];

  const int tid  = threadIdx.x;
  const int lane = tid & 63;
  const int wid  = tid >> 6;
  const int wr   = wid >> 1;      // 2x2 wave grid, each wave 64x64
  const int wc   = wid & 1;
  const int lr   = lane & 15;
  const int lg   = lane >> 4;

  const int bm = blockIdx.y * 128;
  const int bn = blockIdx.x * 128;

  // staging: LDS row-major [128 rows][64 k] bf16 (128 B/row); wave w stages rows w*32..w*32+31
  const int sboff = wid * 4096;              // uniform LDS byte base (per wave)
  const int soff  = sboff + lane * 16;       // this lane's landing byte (j=0)
  const int srow  = soff >> 7;
  const int scol  = (soff & 127) >> 1;

  const bf16* Ag = A  + (long)(bm + srow) * K + scol;
  const bf16* Bg = BT + (long)(bn + srow) * K + scol;
  bf16* Asl = As + (sboff >> 1);
  bf16* Bsl = Bs + (sboff >> 1);

  f32x4 acc[4][4] = {};

  for (int k0 = 0; k0 < K; k0 += 64) {
    #pragma unroll
    for (int j = 0; j < 4; ++j) {           // +j*1024 B = +8 rows
      GLOAD_LDS16(Ag + (long)(j * 8) * K + k0, Asl + j * 512);
      GLOAD_LDS16(Bg + (long)(j * 8) * K + k0, Bsl + j * 512);
    }
    __syncthreads();                          // vmcnt(0) drain + barrier
    #pragma unroll
    for (int kk = 0; kk < 64; kk += 32) {
      short8 af[4], bfm[4];
      #pragma unroll
      for (int m = 0; m < 4; ++m)
        af[m] = *(const short8*)(As + (wr * 64 + m * 16 + lr) * 64 + kk + lg * 8);
      #pragma unroll
      for (int n = 0; n < 4; ++n)
        bfm[n] = *(const short8*)(Bs + (wc * 64 + n * 16 + lr) * 64 + kk + lg * 8);
      #pragma unroll
      for (int m = 0; m < 4; ++m)
        #pragma unroll
        for (int n = 0; n < 4; ++n)
          acc[m][n] = mfma_16x16x32(af[m], bfm[n], acc[m][n]);
    }
    __syncthreads();
  }

  // epilogue: lane holds C[row0 + m*16 + r][col0 + n*16], row0=(..)+lg*4, col0=(..)+lr
  const int row0 = bm + wr * 64 + lg * 4;
  const int col0 = bn + wc * 64 + lr;
  #pragma unroll
  for (int n = 0; n < 4; ++n) {
    const int col = col0 + n * 16;
    const float bv = BIAS ? bias[col] : 0.0f;
    #pragma unroll
    for (int m = 0; m < 4; ++m) {
      #pragma unroll
      for (int r = 0; r < 4; ++r) {
        const long row = row0 + m * 16 + r;
        const float v = acc[m][n][r] + bv;
        if (OUTF32) ((float*)Cout)[row * N + col] = v;
        else        ((bf16*)Cout)[row * N + col] = __float2bfloat16(v);
      }
    }
  }
}

// ---------------- RMSNorm over q,k head rows (128 elems), one wave per row ----------------
__global__ __launch_bounds__(256)
void rmsnorm_qk(bf16* __restrict__ qkv, const float* __restrict__ qw,
                const float* __restrict__ kw) {
  const int row  = blockIdx.x * 4 + (threadIdx.x >> 6);   // 2048*48 rows
  const int lane = threadIdx.x & 63;
  const int token = row / 48;
  const int rem   = row - token * 48;
  const int which = rem / 24;          // 0 = q, 1 = k
  const int head  = rem - which * 24;
  bf16* p = qkv + (long)token * QKVN + which * HID + head * HD;
  const float a = __bfloat162float(p[lane * 2]);
  const float b = __bfloat162float(p[lane * 2 + 1]);
  float ss = a * a + b * b;
  #pragma unroll
  for (int mask = 32; mask >= 1; mask >>= 1) ss += __shfl_xor(ss, mask);
  const float inv = rsqrtf(ss * (1.0f / 128.0f) + 1e-6f);
  const float* w = which ? kw : qw;
  p[lane * 2]     = __float2bfloat16(a * inv * w[lane * 2]);
  p[lane * 2 + 1] = __float2bfloat16(b * inv * w[lane * 2 + 1]);
}

// ---------------- flash attention: block = (64 q rows, 1 head), 4 waves x 16 rows ----------------
__global__ __launch_bounds__(256, 2)
void attn_kernel(const bf16* __restrict__ qkv, bf16* __restrict__ ctx) {
  const int head = blockIdx.y;
  const int qb   = blockIdx.x;
  const int tid  = threadIdx.x;
  const int lane = tid & 63;
  const int wid  = tid >> 6;
  const int lr   = lane & 15;
  const int lg   = lane >> 4;

  __shared__ __align__(16) unsigned short Ks[64 * 136];    // [key][d], padded (+8) vs 128
  __shared__ __align__(16) unsigned short Vt[128 * 72];    // [d][key], padded (+8) vs 64
  __shared__ __align__(16) unsigned short Ps[4][16 * 72];  // per-wave P tile [qrow][key]

  // Q fragments in registers: wave handles q rows qrow0..qrow0+15
  const int qrow0 = qb * 64 + wid * 16;
  short8 qf[4];
  #pragma unroll
  for (int kt = 0; kt < 4; ++kt)
    qf[kt] = *(const short8*)(qkv + (long)(qrow0 + lr) * QKVN + head * HD + kt * 32 + lg * 8);

  f32x4 oacc[8] = {};
  float mrun[4], lrun[4];
  #pragma unroll
  for (int r = 0; r < 4; ++r) { mrun[r] = -1e30f; lrun[r] = 0.0f; }

  const float scale = 0.088388347648318447f;   // 1/sqrt(128)

  for (int t = 0; t < SEQ / 64; ++t) {
    const int kv0 = t * 64;
    // load K,V tile to regs (coalesced 16B chunks): 1024 chunks = 64 tokens x 16 d-chunks
    short8 kreg[4], vreg[4];
    int tokv[4], dchv[4];
    #pragma unroll
    for (int j = 0; j < 4; ++j) {
      const int id  = tid + j * 256;
      const int tok = id >> 4;
      const int dc  = id & 15;
      tokv[j] = tok; dchv[j] = dc;
      kreg[j] = *(const short8*)(qkv + (long)(kv0 + tok) * QKVN + HID     + head * HD + dc * 8);
      vreg[j] = *(const short8*)(qkv + (long)(kv0 + tok) * QKVN + 2 * HID + head * HD + dc * 8);
    }
    __syncthreads();   // previous tile's compute done before overwriting LDS
    #pragma unroll
    for (int j = 0; j < 4; ++j) {
      *(short8*)&Ks[tokv[j] * 136 + dchv[j] * 8] = kreg[j];
      #pragma unroll
      for (int i = 0; i < 8; ++i)
        Vt[(dchv[j] * 8 + i) * 72 + tokv[j]] = (unsigned short)vreg[j][i];
    }
    __syncthreads();

    // S = Q(16x128) . K^T(128x64): 4 col-tiles x 4 k-frags
    f32x4 s[4];
    #pragma unroll
    for (int ct = 0; ct < 4; ++ct) {
      f32x4 a = {};
      #pragma unroll
      for (int kt = 0; kt < 4; ++kt) {
        short8 kb = *(const short8*)&Ks[(ct * 16 + lr) * 136 + kt * 32 + lg * 8];
        a = mfma_16x16x32(qf[kt], kb, a);
      }
      s[ct] = a;
    }

    // online softmax per q-row (lane's rows: lg*4 + r; cols: lr + 16*ct)
    #pragma unroll
    for (int r = 0; r < 4; ++r) {
      float pm = fmaxf(fmaxf(s[0][r], s[1][r]), fmaxf(s[2][r], s[3][r]));
      #pragma unroll
      for (int mask = 1; mask <= 8; mask <<= 1) pm = fmaxf(pm, __shfl_xor(pm, mask));
      pm *= scale;
      const float mnew = fmaxf(mrun[r], pm);
      const float corr = __expf(mrun[r] - mnew);
      float psum = 0.0f;
      #pragma unroll
      for (int ct = 0; ct < 4; ++ct) {
        const float p = __expf(s[ct][r] * scale - mnew);
        psum += p;
        bf16 pb = __float2bfloat16(p);
        Ps[wid][(lg * 4 + r) * 72 + ct * 16 + lr] = *(unsigned short*)&pb;
      }
      #pragma unroll
      for (int mask = 1; mask <= 8; mask <<= 1) psum += __shfl_xor(psum, mask);
      lrun[r] = lrun[r] * corr + psum;
      mrun[r] = mnew;
      #pragma unroll
      for (int dt = 0; dt < 8; ++dt) oacc[dt][r] *= corr;
    }

    // O += P(16x64) . V(64x128)
    short8 pa[2];
    #pragma unroll
    for (int kt = 0; kt < 2; ++kt)
      pa[kt] = *(const short8*)&Ps[wid][lr * 72 + kt * 32 + lg * 8];
    #pragma unroll
    for (int dt = 0; dt < 8; ++dt) {
      #pragma unroll
      for (int kt = 0; kt < 2; ++kt) {
        short8 vb = *(const short8*)&Vt[(dt * 16 + lr) * 72 + kt * 32 + lg * 8];
        oacc[dt] = mfma_16x16x32(pa[kt], vb, oacc[dt]);
      }
    }
  }

  // epilogue: ctx[token][head*128 + d] = O / l
  #pragma unroll
  for (int r = 0; r < 4; ++r) {
    const float inv = 1.0f / lrun[r];
    const long tok = qrow0 + lg * 4 + r;
    #pragma unroll
    for (int dt = 0; dt < 8; ++dt)
      ctx[tok * HID + head * HD + dt * 16 + lr] = __float2bfloat16(oacc[dt][r] * inv);
  }
}

extern "C" void kernel_launch(void* const* d_in, const int* in_sizes, int n_in,
                              void* d_out, int out_size, void* d_ws, size_t ws_size,
                              hipStream_t stream) {
  (void)in_sizes; (void)n_in; (void)out_size; (void)ws_size;
  const float* x     = (const float*)d_in[0];
  const float* Wqkv  = (const float*)d_in[1];
  const float* bqkv  = (const float*)d_in[2];
  const float* Wproj = (const float*)d_in[3];
  const float* qw    = (const float*)d_in[4];
  const float* kw    = (const float*)d_in[5];

  char* ws = (char*)d_ws;                       // total 125,829,120 B used
  bf16* xb     = (bf16*)ws;                     // 2048x3072 bf16 (12.58 MB)
  bf16* WqkvT  = (bf16*)(ws + 12582912);        // 9216x3072 bf16 (56.62 MB)
  bf16* WprojT = (bf16*)(ws + 69206016);        // 3072x3072 bf16 (18.87 MB)
  bf16* qkv    = (bf16*)(ws + 88080384);        // 2048x9216 bf16 (37.75 MB)
  bf16* ctx    = xb;                            // xb dead after GEMM1 -> reuse for ctx

  cvt_f32_bf16_vec<<<(SEQ * HID / 4 + 255) / 256, 256, 0, stream>>>(x, xb, SEQ * HID / 4);
  transpose_cvt<<<dim3(QKVN / 32, HID / 32), 256, 0, stream>>>(Wqkv, WqkvT, HID, QKVN);
  transpose_cvt<<<dim3(HID / 32, HID / 32), 256, 0, stream>>>(Wproj, WprojT, HID, HID);

  gemm_bt<1, 0><<<dim3(QKVN / 128, SEQ / 128), 256, 0, stream>>>(
      xb, WqkvT, bqkv, (void*)qkv, SEQ, QKVN, HID);

  rmsnorm_qk<<<SEQ * 48 / 4, 256, 0, stream>>>(qkv, qw, kw);

  attn_kernel<<<dim3(SEQ / 64, NH), 256, 0, stream>>>(qkv, ctx);

  gemm_bt<0, 1><<<dim3(HID / 128, SEQ / 128), 256, 0, stream>>>(
      ctx, WprojT, nullptr, d_out, SEQ, HID, HID);
}

// Round 2
// 408.319 us; speedup vs baseline: 1.3752x; 1.3752x over previous
//
#include <hip/hip_runtime.h>
#include <hip/hip_bf16.h>

using bf16 = __hip_bfloat16;
typedef __attribute__((ext_vector_type(8))) short short8;   // 8 x bf16 fragment (4 VGPRs)
typedef __attribute__((ext_vector_type(4))) float f32x4;
typedef unsigned long long ull;

static constexpr int SEQ  = 2048;
static constexpr int HID  = 3072;
static constexpr int NH   = 24;
static constexpr int HD   = 128;
static constexpr int QKVN = 9216;

__device__ __forceinline__ f32x4 mfma_16x16x32(short8 a, short8 b, f32x4 c) {
  return __builtin_amdgcn_mfma_f32_16x16x32_bf16(a, b, c, 0, 0, 0);
}

#define GLOAD_LDS16(g, l) __builtin_amdgcn_global_load_lds(                 \
    (const __attribute__((address_space(1))) void*)(g),                    \
    (__attribute__((address_space(3))) void*)(l), 16, 0, 0)

typedef __attribute__((address_space(3))) const unsigned char lds_cchar;

// ---------------- fp32 -> bf16 vectorized convert ----------------
__global__ __launch_bounds__(256)
void cvt_f32_bf16_vec(const float* __restrict__ src, bf16* __restrict__ dst, int n4) {
  int i = blockIdx.x * 256 + threadIdx.x;
  if (i >= n4) return;
  float4 v = ((const float4*)src)[i];
  ushort4 o;
  bf16 t0 = __float2bfloat16(v.x); o.x = *(unsigned short*)&t0;
  bf16 t1 = __float2bfloat16(v.y); o.y = *(unsigned short*)&t1;
  bf16 t2 = __float2bfloat16(v.z); o.z = *(unsigned short*)&t2;
  bf16 t3 = __float2bfloat16(v.w); o.w = *(unsigned short*)&t3;
  ((ushort4*)dst)[i] = o;
}

// ---------------- fp32 (R x C) -> bf16 transposed (C x R) ----------------
__global__ __launch_bounds__(256)
void transpose_cvt(const float* __restrict__ src, bf16* __restrict__ dst, int R, int C) {
  __shared__ float tile[32][33];
  const int c0 = blockIdx.x * 32, r0 = blockIdx.y * 32;
  const int tc = threadIdx.x & 31, tr = threadIdx.x >> 5;
  #pragma unroll
  for (int i = 0; i < 4; ++i)
    tile[tr + i * 8][tc] = src[(long)(r0 + tr + i * 8) * C + c0 + tc];
  __syncthreads();
  #pragma unroll
  for (int i = 0; i < 4; ++i)
    dst[(long)(c0 + tr + i * 8) * R + r0 + tc] = __float2bfloat16(tile[tc][tr + i * 8]);
}

// ---------------- GEMM: C[M,N] = A[M,K] * BT[N,K]^T (+bias), m97 structure ----------------
template<int BIAS, int OUTF32>
__global__ __launch_bounds__(256, 2)
void gemm_bt(const bf16* __restrict__ A, const bf16* __restrict__ BT,
             const float* __restrict__ bias, void* __restrict__ Cout,
             int M, int N, int K) {
  __shared__ __align__(16) bf16 As[128 * 64];
  __shared__ __align__(16) bf16 Bs[128 * 64];

  const int tid  = threadIdx.x;
  const int lane = tid & 63;
  const int wid  = tid >> 6;
  const int wr   = wid >> 1;      // 2x2 wave grid, each wave 64x64
  const int wc   = wid & 1;
  const int lr   = lane & 15;
  const int lg   = lane >> 4;

  const int bm = blockIdx.y * 128;
  const int bn = blockIdx.x * 128;

  // staging: LDS row-major [128 rows][64 k] bf16 (128 B/row); wave w stages rows w*32..w*32+31
  const int sboff = wid * 4096;              // uniform LDS byte base (per wave)
  const int soff  = sboff + lane * 16;       // this lane's landing byte (j=0)
  const int srow  = soff >> 7;
  const int scol  = (soff & 127) >> 1;

  const bf16* Ag = A  + (long)(bm + srow) * K + scol;
  const bf16* Bg = BT + (long)(bn + srow) * K + scol;
  bf16* Asl = As + (sboff >> 1);
  bf16* Bsl = Bs + (sboff >> 1);

  f32x4 acc[4][4] = {};

  for (int k0 = 0; k0 < K; k0 += 64) {
    #pragma unroll
    for (int j = 0; j < 4; ++j) {           // +j*1024 B = +8 rows
      GLOAD_LDS16(Ag + (long)(j * 8) * K + k0, Asl + j * 512);
      GLOAD_LDS16(Bg + (long)(j * 8) * K + k0, Bsl + j * 512);
    }
    __syncthreads();                          // vmcnt(0) drain + barrier
    #pragma unroll
    for (int kk = 0; kk < 64; kk += 32) {
      short8 af[4], bfm[4];
      #pragma unroll
      for (int m = 0; m < 4; ++m)
        af[m] = *(const short8*)(As + (wr * 64 + m * 16 + lr) * 64 + kk + lg * 8);
      #pragma unroll
      for (int n = 0; n < 4; ++n)
        bfm[n] = *(const short8*)(Bs + (wc * 64 + n * 16 + lr) * 64 + kk + lg * 8);
      #pragma unroll
      for (int m = 0; m < 4; ++m)
        #pragma unroll
        for (int n = 0; n < 4; ++n)
          acc[m][n] = mfma_16x16x32(af[m], bfm[n], acc[m][n]);
    }
    __syncthreads();
  }

  // epilogue: lane holds C[row0 + m*16 + r][col0 + n*16], row0=(..)+lg*4, col0=(..)+lr
  const int row0 = bm + wr * 64 + lg * 4;
  const int col0 = bn + wc * 64 + lr;
  #pragma unroll
  for (int n = 0; n < 4; ++n) {
    const int col = col0 + n * 16;
    const float bv = BIAS ? bias[col] : 0.0f;
    #pragma unroll
    for (int m = 0; m < 4; ++m) {
      #pragma unroll
      for (int r = 0; r < 4; ++r) {
        const long row = row0 + m * 16 + r;
        const float v = acc[m][n][r] + bv;
        if (OUTF32) ((float*)Cout)[row * N + col] = v;
        else        ((bf16*)Cout)[row * N + col] = __float2bfloat16(v);
      }
    }
  }
}

// ---------------- RMSNorm over q,k head rows (128 elems), one wave per row ----------------
__global__ __launch_bounds__(256)
void rmsnorm_qk(bf16* __restrict__ qkv, const float* __restrict__ qw,
                const float* __restrict__ kw) {
  const int row  = blockIdx.x * 4 + (threadIdx.x >> 6);   // 2048*48 rows
  const int lane = threadIdx.x & 63;
  const int token = row / 48;
  const int rem   = row - token * 48;
  const int which = rem / 24;          // 0 = q, 1 = k
  const int head  = rem - which * 24;
  bf16* p = qkv + (long)token * QKVN + which * HID + head * HD;
  const float a = __bfloat162float(p[lane * 2]);
  const float b = __bfloat162float(p[lane * 2 + 1]);
  float ss = a * a + b * b;
  #pragma unroll
  for (int mask = 32; mask >= 1; mask >>= 1) ss += __shfl_xor(ss, mask);
  const float inv = rsqrtf(ss * (1.0f / 128.0f) + 1e-6f);
  const float* w = which ? kw : qw;
  p[lane * 2]     = __float2bfloat16(a * inv * w[lane * 2]);
  p[lane * 2 + 1] = __float2bfloat16(b * inv * w[lane * 2 + 1]);
}

// ---------------- flash attention: block = (64 q rows, 1 head), 4 waves x 16 rows ----------------
// K: LDS row-major [64][128] bf16, XOR-swizzled byte^=((row&7)<<4)  (T2, m214 recipe)
// V: LDS 4x16-subtiled [dg:8][pos:16][4key][16d], pos = (kg&8)|((kg&1)<<2)|((kg>>1)&3);
//    read via ds_read_b64_tr_b16 (T10): per-lane addr base+lane*8, group lg -> subtile pos base/128+lg
__global__ __launch_bounds__(256, 2)
void attn_kernel(const bf16* __restrict__ qkv, bf16* __restrict__ ctx) {
  const int head = blockIdx.y;
  const int qb   = blockIdx.x;
  const int tid  = threadIdx.x;
  const int lane = tid & 63;
  const int wid  = tid >> 6;
  const int lr   = lane & 15;
  const int lg   = lane >> 4;

  __shared__ __align__(16) unsigned char Ksb[64 * 256];      // 16 KB, swizzled rows
  __shared__ __align__(16) unsigned char Vsb[128 * 128];     // 16 KB, subtiled
  __shared__ __align__(16) unsigned short Ps[4][16 * 72];    // per-wave P tile [qrow][key]

  // Q fragments in registers: wave handles q rows qrow0..qrow0+15
  const int qrow0 = qb * 64 + wid * 16;
  short8 qf[4];
  #pragma unroll
  for (int kt = 0; kt < 4; ++kt)
    qf[kt] = *(const short8*)(qkv + (long)(qrow0 + lr) * QKVN + head * HD + kt * 32 + lg * 8);

  f32x4 oacc[8] = {};
  float mrun[4], lrun[4];
  #pragma unroll
  for (int r = 0; r < 4; ++r) { mrun[r] = -1e30f; lrun[r] = 0.0f; }

  const float scale = 0.088388347648318447f;   // 1/sqrt(128)

  for (int t = 0; t < SEQ / 64; ++t) {
    const int kv0 = t * 64;
    // load K,V tile to regs (coalesced 16B chunks): 1024 chunks = 64 tokens x 16 d-chunks
    short8 kreg[4], vreg[4];
    int tokv[4], dchv[4];
    #pragma unroll
    for (int j = 0; j < 4; ++j) {
      const int id  = tid + j * 256;
      const int tok = id >> 4;
      const int dc  = id & 15;
      tokv[j] = tok; dchv[j] = dc;
      kreg[j] = *(const short8*)(qkv + (long)(kv0 + tok) * QKVN + HID     + head * HD + dc * 8);
      vreg[j] = *(const short8*)(qkv + (long)(kv0 + tok) * QKVN + 2 * HID + head * HD + dc * 8);
    }
    __syncthreads();   // previous tile's compute done before overwriting LDS
    #pragma unroll
    for (int j = 0; j < 4; ++j) {
      const int tok = tokv[j], dc = dchv[j];
      // K: row-major swizzled
      *(short8*)(Ksb + ((tok * 256 + dc * 16) ^ ((tok & 7) << 4))) = kreg[j];
      // V: subtiled; this chunk = keys tok, d = dc*8..dc*8+7 (one dg, half a subtile row)
      const int dg = dc >> 1, h = dc & 1, kg = tok >> 2, kr = tok & 3;
      const int pos = (kg & 8) | ((kg & 1) << 2) | ((kg >> 1) & 3);
      *(short8*)(Vsb + (dg * 16 + pos) * 128 + kr * 32 + h * 16) = vreg[j];
    }
    __syncthreads();

    // S = Q(16x128) . K^T(128x64): 4 col-tiles x 4 k-frags
    f32x4 s[4];
    __builtin_amdgcn_s_setprio(1);
    #pragma unroll
    for (int ct = 0; ct < 4; ++ct) {
      f32x4 a = {};
      #pragma unroll
      for (int kt = 0; kt < 4; ++kt) {
        short8 kb = *(const short8*)(Ksb +
            ((((ct * 16 + lr) * 256) + kt * 64 + lg * 16) ^ ((lr & 7) << 4)));
        a = mfma_16x16x32(qf[kt], kb, a);
      }
      s[ct] = a;
    }
    __builtin_amdgcn_s_setprio(0);

    // online softmax per q-row (lane's rows: lg*4 + r; cols: lr + 16*ct)
    #pragma unroll
    for (int r = 0; r < 4; ++r) {
      float pm = fmaxf(fmaxf(s[0][r], s[1][r]), fmaxf(s[2][r], s[3][r]));
      #pragma unroll
      for (int mask = 1; mask <= 8; mask <<= 1) pm = fmaxf(pm, __shfl_xor(pm, mask));
      pm *= scale;
      const float mnew = fmaxf(mrun[r], pm);
      const float corr = __expf(mrun[r] - mnew);
      float psum = 0.0f;
      #pragma unroll
      for (int ct = 0; ct < 4; ++ct) {
        const float p = __expf(s[ct][r] * scale - mnew);
        psum += p;
        bf16 pb = __float2bfloat16(p);
        Ps[wid][(lg * 4 + r) * 72 + ct * 16 + lr] = *(unsigned short*)&pb;
      }
      #pragma unroll
      for (int mask = 1; mask <= 8; mask <<= 1) psum += __shfl_xor(psum, mask);
      lrun[r] = lrun[r] * corr + psum;
      mrun[r] = mnew;
      #pragma unroll
      for (int dt = 0; dt < 8; ++dt) oacc[dt][r] *= corr;
    }

    // O += P(16x64) . V(64x128): V b-frags via hardware transpose reads
    short8 pa[2];
    #pragma unroll
    for (int kt = 0; kt < 2; ++kt)
      pa[kt] = *(const short8*)&Ps[wid][lr * 72 + kt * 32 + lg * 8];

    lds_cchar* vb0 = (lds_cchar*)Vsb + lane * 8;
    __builtin_amdgcn_s_setprio(1);
    #pragma unroll
    for (int dt = 0; dt < 8; ++dt) {
      lds_cchar* pd = vb0 + dt * 2048;
      ull r0, r1, r2, r3;
      asm volatile("ds_read_b64_tr_b16 %0, %1 offset:0"    : "=v"(r0) : "v"(pd));
      asm volatile("ds_read_b64_tr_b16 %0, %1 offset:512"  : "=v"(r1) : "v"(pd));
      asm volatile("ds_read_b64_tr_b16 %0, %1 offset:1024" : "=v"(r2) : "v"(pd));
      asm volatile("ds_read_b64_tr_b16 %0, %1 offset:1536" : "=v"(r3) : "v"(pd));
      asm volatile("s_waitcnt lgkmcnt(0)" ::: "memory");
      __builtin_amdgcn_sched_barrier(0);
      short8 vb_0, vb_1;
      ((ull*)&vb_0)[0] = r0; ((ull*)&vb_0)[1] = r1;
      ((ull*)&vb_1)[0] = r2; ((ull*)&vb_1)[1] = r3;
      oacc[dt] = mfma_16x16x32(pa[0], vb_0, oacc[dt]);
      oacc[dt] = mfma_16x16x32(pa[1], vb_1, oacc[dt]);
    }
    __builtin_amdgcn_s_setprio(0);
  }

  // epilogue: ctx[token][head*128 + d] = O / l
  #pragma unroll
  for (int r = 0; r < 4; ++r) {
    const float inv = 1.0f / lrun[r];
    const long tok = qrow0 + lg * 4 + r;
    #pragma unroll
    for (int dt = 0; dt < 8; ++dt)
      ctx[tok * HID + head * HD + dt * 16 + lr] = __float2bfloat16(oacc[dt][r] * inv);
  }
}

extern "C" void kernel_launch(void* const* d_in, const int* in_sizes, int n_in,
                              void* d_out, int out_size, void* d_ws, size_t ws_size,
                              hipStream_t stream) {
  (void)in_sizes; (void)n_in; (void)out_size; (void)ws_size;
  const float* x     = (const float*)d_in[0];
  const float* Wqkv  = (const float*)d_in[1];
  const float* bqkv  = (const float*)d_in[2];
  const float* Wproj = (const float*)d_in[3];
  const float* qw    = (const float*)d_in[4];
  const float* kw    = (const float*)d_in[5];

  char* ws = (char*)d_ws;                       // total 125,829,120 B used
  bf16* xb     = (bf16*)ws;                     // 2048x3072 bf16 (12.58 MB)
  bf16* WqkvT  = (bf16*)(ws + 12582912);        // 9216x3072 bf16 (56.62 MB)
  bf16* WprojT = (bf16*)(ws + 69206016);        // 3072x3072 bf16 (18.87 MB)
  bf16* qkv    = (bf16*)(ws + 88080384);        // 2048x9216 bf16 (37.75 MB)
  bf16* ctx    = xb;                            // xb dead after GEMM1 -> reuse for ctx

  cvt_f32_bf16_vec<<<(SEQ * HID / 4 + 255) / 256, 256, 0, stream>>>(x, xb, SEQ * HID / 4);
  transpose_cvt<<<dim3(QKVN / 32, HID / 32), 256, 0, stream>>>(Wqkv, WqkvT, HID, QKVN);
  transpose_cvt<<<dim3(HID / 32, HID / 32), 256, 0, stream>>>(Wproj, WprojT, HID, HID);

  gemm_bt<1, 0><<<dim3(QKVN / 128, SEQ / 128), 256, 0, stream>>>(
      xb, WqkvT, bqkv, (void*)qkv, SEQ, QKVN, HID);

  rmsnorm_qk<<<SEQ * 48 / 4, 256, 0, stream>>>(qkv, qw, kw);

  attn_kernel<<<dim3(SEQ / 64, NH), 256, 0, stream>>>(qkv, ctx);

  gemm_bt<0, 1><<<dim3(HID / 128, SEQ / 128), 256, 0, stream>>>(
      ctx, WprojT, nullptr, d_out, SEQ, HID, HID);
}

// Round 3
// 395.577 us; speedup vs baseline: 1.4195x; 1.0322x over previous
//
#include <hip/hip_runtime.h>
#include <hip/hip_bf16.h>

using bf16 = __hip_bfloat16;
typedef __attribute__((ext_vector_type(8))) short short8;   // 8 x bf16 fragment (4 VGPRs)
typedef __attribute__((ext_vector_type(4))) float f32x4;
typedef unsigned long long ull;

static constexpr int SEQ  = 2048;
static constexpr int HID  = 3072;
static constexpr int NH   = 24;
static constexpr int HD   = 128;
static constexpr int QKVN = 9216;

__device__ __forceinline__ f32x4 mfma_16x16x32(short8 a, short8 b, f32x4 c) {
  return __builtin_amdgcn_mfma_f32_16x16x32_bf16(a, b, c, 0, 0, 0);
}

#define GLOAD_LDS16(g, l) __builtin_amdgcn_global_load_lds(                 \
    (const __attribute__((address_space(1))) void*)(g),                    \
    (__attribute__((address_space(3))) void*)(l), 16, 0, 0)

typedef __attribute__((address_space(3))) const unsigned char lds_cchar;

// ---------------- fp32 -> bf16 vectorized convert ----------------
__global__ __launch_bounds__(256)
void cvt_f32_bf16_vec(const float* __restrict__ src, bf16* __restrict__ dst, int n4) {
  int i = blockIdx.x * 256 + threadIdx.x;
  if (i >= n4) return;
  float4 v = ((const float4*)src)[i];
  ushort4 o;
  bf16 t0 = __float2bfloat16(v.x); o.x = *(unsigned short*)&t0;
  bf16 t1 = __float2bfloat16(v.y); o.y = *(unsigned short*)&t1;
  bf16 t2 = __float2bfloat16(v.z); o.z = *(unsigned short*)&t2;
  bf16 t3 = __float2bfloat16(v.w); o.w = *(unsigned short*)&t3;
  ((ushort4*)dst)[i] = o;
}

// ---------------- fp32 (R x C) -> bf16 transposed (C x R) ----------------
__global__ __launch_bounds__(256)
void transpose_cvt(const float* __restrict__ src, bf16* __restrict__ dst, int R, int C) {
  __shared__ float tile[32][33];
  const int c0 = blockIdx.x * 32, r0 = blockIdx.y * 32;
  const int tc = threadIdx.x & 31, tr = threadIdx.x >> 5;
  #pragma unroll
  for (int i = 0; i < 4; ++i)
    tile[tr + i * 8][tc] = src[(long)(r0 + tr + i * 8) * C + c0 + tc];
  __syncthreads();
  #pragma unroll
  for (int i = 0; i < 4; ++i)
    dst[(long)(c0 + tr + i * 8) * R + r0 + tc] = __float2bfloat16(tile[tc][tr + i * 8]);
}

// ---------------- GEMM: C[M,N] = A[M,K] * BT[N,K]^T (+bias) ----------------
// BM=256, BN=128, BK=64; 512 threads = 8 waves (4M x 2N), per-wave 64x64 output.
// Triple-buffered LDS (144 KiB): stage tile t+2 into buf[(t+2)%3] while computing
// buf[t%3] -> staging never targets a buffer being read (race-free), ~2 K-tiles of
// load flight. One counted s_waitcnt vmcnt(6) per K-tile (never 0 in steady state).
// T2 swizzle: LDS chunk c of row r holds global chunk c^(r&7) (pre-swizzled source,
// linear global_load_lds dest); reads XOR the same way -> b128 at the bank floor.
template<int BIAS, int OUTF32>
__global__ __launch_bounds__(512, 2)
void gemm_pipe(const bf16* __restrict__ A, const bf16* __restrict__ BT,
               const float* __restrict__ bias, void* __restrict__ Cout,
               int M, int N, int K, int nbn) {
  __shared__ __align__(16) bf16 Asb[3][256 * 64];
  __shared__ __align__(16) bf16 Bsb[3][128 * 64];

  const int tid  = threadIdx.x;
  const int lane = tid & 63;
  const int wid  = tid >> 6;
  const int wr   = wid >> 1;    // 0..3 (M)
  const int wc   = wid & 1;     // 0..1 (N)
  const int lr   = lane & 15;
  const int lg   = lane >> 4;

  // XCD-aware swizzle (nwg % 8 == 0 for both GEMMs): XCD x gets a contiguous
  // chunk of work ids -> one M-row of tiles per XCD (A-panel L2-resident).
  const int nwg = gridDim.x;
  const int cpx = nwg >> 3;
  const int w   = (blockIdx.x & 7) * cpx + (blockIdx.x >> 3);
  const int bm  = (w / nbn) * 256;
  const int bn  = (w % nbn) * 128;

  // staging: each global_load_lds covers 64 rows x 64 k (8 KB, 512 thr x 16 B)
  const int rl   = wid * 8 + (lane >> 3);            // row within 64-row block
  const int csrc = ((lane & 7) ^ (lane >> 3)) * 8;   // pre-swizzled source chunk
  const bf16* Ag = A  + (size_t)(bm + rl) * K + csrc;
  const bf16* Bg = BT + (size_t)(bn + rl) * K + csrc;

#define STAGE_A(b, u, j) GLOAD_LDS16(Ag + (size_t)((j) * 64) * K + (u) * 64,  \
                                     Asb[b] + ((j) * 64 + wid * 8) * 64)
#define STAGE_B(b, u, j) GLOAD_LDS16(Bg + (size_t)((j) * 64) * K + (u) * 64,  \
                                     Bsb[b] + ((j) * 64 + wid * 8) * 64)
  // read fragment: row = (warp block) + frag*16 + lr; chunk = (kk*4+lg) ^ (lr&7)
#define RD_A(b, m, kk) (*(const short8*)(Asb[b] + (wr * 64 + (m) * 16 + lr) * 64 \
                          + ((((kk) * 4 + lg) ^ (lr & 7)) * 8)))
#define RD_B(b, n, kk) (*(const short8*)(Bsb[b] + (wc * 64 + (n) * 16 + lr) * 64 \
                          + ((((kk) * 4 + lg) ^ (lr & 7)) * 8)))

  f32x4 acc[4][4] = {};
  const int NT = K >> 6;

  // prologue: stage tiles 0 and 1 (6 loads each); wait for tile 0 only
  #pragma unroll
  for (int j = 0; j < 4; ++j) STAGE_A(0, 0, j);
  STAGE_B(0, 0, 0); STAGE_B(0, 0, 1);
  #pragma unroll
  for (int j = 0; j < 4; ++j) STAGE_A(1, 1, j);
  STAGE_B(1, 1, 0); STAGE_B(1, 1, 1);
  asm volatile("s_waitcnt vmcnt(6)" ::: "memory");
  __builtin_amdgcn_s_barrier();

  int cur = 0;
  for (int t = 0; t < NT; ++t) {
    int nxt2 = cur + 2; if (nxt2 >= 3) nxt2 -= 3;
    const bool pf = (t + 2) < NT;

    // ---- phase 1: A (all 8 frags) + B n0/n1; stage 3 of tile t+2; MFMA n-half 0
    short8 a0 = RD_A(cur, 0, 0), a1 = RD_A(cur, 1, 0), a2 = RD_A(cur, 2, 0), a3 = RD_A(cur, 3, 0);
    short8 a4 = RD_A(cur, 0, 1), a5 = RD_A(cur, 1, 1), a6 = RD_A(cur, 2, 1), a7 = RD_A(cur, 3, 1);
    short8 b0 = RD_B(cur, 0, 0), b1 = RD_B(cur, 1, 0), b2 = RD_B(cur, 0, 1), b3 = RD_B(cur, 1, 1);
    if (pf) { STAGE_A(nxt2, t + 2, 0); STAGE_A(nxt2, t + 2, 1); STAGE_A(nxt2, t + 2, 2); }
    __builtin_amdgcn_sched_barrier(0);
    __builtin_amdgcn_s_barrier();
    __builtin_amdgcn_s_setprio(1);
    acc[0][0] = mfma_16x16x32(a0, b0, acc[0][0]);
    acc[1][0] = mfma_16x16x32(a1, b0, acc[1][0]);
    acc[2][0] = mfma_16x16x32(a2, b0, acc[2][0]);
    acc[3][0] = mfma_16x16x32(a3, b0, acc[3][0]);
    acc[0][1] = mfma_16x16x32(a0, b1, acc[0][1]);
    acc[1][1] = mfma_16x16x32(a1, b1, acc[1][1]);
    acc[2][1] = mfma_16x16x32(a2, b1, acc[2][1]);
    acc[3][1] = mfma_16x16x32(a3, b1, acc[3][1]);
    acc[0][0] = mfma_16x16x32(a4, b2, acc[0][0]);
    acc[1][0] = mfma_16x16x32(a5, b2, acc[1][0]);
    acc[2][0] = mfma_16x16x32(a6, b2, acc[2][0]);
    acc[3][0] = mfma_16x16x32(a7, b2, acc[3][0]);
    acc[0][1] = mfma_16x16x32(a4, b3, acc[0][1]);
    acc[1][1] = mfma_16x16x32(a5, b3, acc[1][1]);
    acc[2][1] = mfma_16x16x32(a6, b3, acc[2][1]);
    acc[3][1] = mfma_16x16x32(a7, b3, acc[3][1]);
    __builtin_amdgcn_s_setprio(0);
    __builtin_amdgcn_s_barrier();

    // ---- phase 2: B n2/n3; stage remaining 3; counted wait; MFMA n-half 1
    short8 c0 = RD_B(cur, 2, 0), c1 = RD_B(cur, 3, 0), c2 = RD_B(cur, 2, 1), c3 = RD_B(cur, 3, 1);
    if (pf) { STAGE_A(nxt2, t + 2, 3); STAGE_B(nxt2, t + 2, 0); STAGE_B(nxt2, t + 2, 1); }
    __builtin_amdgcn_sched_barrier(0);
    if (pf) asm volatile("s_waitcnt vmcnt(6)" ::: "memory");   // tile t+1 landed; t+2 in flight
    else    asm volatile("s_waitcnt vmcnt(0)" ::: "memory");   // drain at the tail
    __builtin_amdgcn_s_barrier();
    __builtin_amdgcn_s_setprio(1);
    acc[0][2] = mfma_16x16x32(a0, c0, acc[0][2]);
    acc[1][2] = mfma_16x16x32(a1, c0, acc[1][2]);
    acc[2][2] = mfma_16x16x32(a2, c0, acc[2][2]);
    acc[3][2] = mfma_16x16x32(a3, c0, acc[3][2]);
    acc[0][3] = mfma_16x16x32(a0, c1, acc[0][3]);
    acc[1][3] = mfma_16x16x32(a1, c1, acc[1][3]);
    acc[2][3] = mfma_16x16x32(a2, c1, acc[2][3]);
    acc[3][3] = mfma_16x16x32(a3, c1, acc[3][3]);
    acc[0][2] = mfma_16x16x32(a4, c2, acc[0][2]);
    acc[1][2] = mfma_16x16x32(a5, c2, acc[1][2]);
    acc[2][2] = mfma_16x16x32(a6, c2, acc[2][2]);
    acc[3][2] = mfma_16x16x32(a7, c2, acc[3][2]);
    acc[0][3] = mfma_16x16x32(a4, c3, acc[0][3]);
    acc[1][3] = mfma_16x16x32(a5, c3, acc[1][3]);
    acc[2][3] = mfma_16x16x32(a6, c3, acc[2][3]);
    acc[3][3] = mfma_16x16x32(a7, c3, acc[3][3]);
    __builtin_amdgcn_s_setprio(0);
    __builtin_amdgcn_s_barrier();

    cur = cur + 1; if (cur == 3) cur = 0;
  }
#undef STAGE_A
#undef STAGE_B
#undef RD_A
#undef RD_B

  // epilogue: lane holds C[row0 + m*16 + r][col0 + n*16]
  const int row0 = bm + wr * 64 + lg * 4;
  const int col0 = bn + wc * 64 + lr;
  #pragma unroll
  for (int n = 0; n < 4; ++n) {
    const int col = col0 + n * 16;
    const float bv = BIAS ? bias[col] : 0.0f;
    #pragma unroll
    for (int m = 0; m < 4; ++m) {
      #pragma unroll
      for (int r = 0; r < 4; ++r) {
        const long row = row0 + m * 16 + r;
        const float v = acc[m][n][r] + bv;
        if (OUTF32) ((float*)Cout)[row * N + col] = v;
        else        ((bf16*)Cout)[row * N + col] = __float2bfloat16(v);
      }
    }
  }
}

// ---------------- RMSNorm over q,k head rows (128 elems), one wave per row ----------------
__global__ __launch_bounds__(256)
void rmsnorm_qk(bf16* __restrict__ qkv, const float* __restrict__ qw,
                const float* __restrict__ kw) {
  const int row  = blockIdx.x * 4 + (threadIdx.x >> 6);   // 2048*48 rows
  const int lane = threadIdx.x & 63;
  const int token = row / 48;
  const int rem   = row - token * 48;
  const int which = rem / 24;          // 0 = q, 1 = k
  const int head  = rem - which * 24;
  bf16* p = qkv + (long)token * QKVN + which * HID + head * HD;
  const float a = __bfloat162float(p[lane * 2]);
  const float b = __bfloat162float(p[lane * 2 + 1]);
  float ss = a * a + b * b;
  #pragma unroll
  for (int mask = 32; mask >= 1; mask >>= 1) ss += __shfl_xor(ss, mask);
  const float inv = rsqrtf(ss * (1.0f / 128.0f) + 1e-6f);
  const float* w = which ? kw : qw;
  p[lane * 2]     = __float2bfloat16(a * inv * w[lane * 2]);
  p[lane * 2 + 1] = __float2bfloat16(b * inv * w[lane * 2 + 1]);
}

// ---------------- flash attention: block = (64 q rows, 1 head), 4 waves x 16 rows ----------------
__global__ __launch_bounds__(256, 2)
void attn_kernel(const bf16* __restrict__ qkv, bf16* __restrict__ ctx) {
  const int head = blockIdx.y;
  const int qb   = blockIdx.x;
  const int tid  = threadIdx.x;
  const int lane = tid & 63;
  const int wid  = tid >> 6;
  const int lr   = lane & 15;
  const int lg   = lane >> 4;

  __shared__ __align__(16) unsigned char Ksb[64 * 256];      // 16 KB, swizzled rows
  __shared__ __align__(16) unsigned char Vsb[128 * 128];     // 16 KB, subtiled
  __shared__ __align__(16) unsigned short Ps[4][16 * 72];    // per-wave P tile [qrow][key]

  const int qrow0 = qb * 64 + wid * 16;
  short8 qf[4];
  #pragma unroll
  for (int kt = 0; kt < 4; ++kt)
    qf[kt] = *(const short8*)(qkv + (long)(qrow0 + lr) * QKVN + head * HD + kt * 32 + lg * 8);

  f32x4 oacc[8] = {};
  float mrun[4], lrun[4];
  #pragma unroll
  for (int r = 0; r < 4; ++r) { mrun[r] = -1e30f; lrun[r] = 0.0f; }

  const float scale = 0.088388347648318447f;   // 1/sqrt(128)

  for (int t = 0; t < SEQ / 64; ++t) {
    const int kv0 = t * 64;
    short8 kreg[4], vreg[4];
    int tokv[4], dchv[4];
    #pragma unroll
    for (int j = 0; j < 4; ++j) {
      const int id  = tid + j * 256;
      const int tok = id >> 4;
      const int dc  = id & 15;
      tokv[j] = tok; dchv[j] = dc;
      kreg[j] = *(const short8*)(qkv + (long)(kv0 + tok) * QKVN + HID     + head * HD + dc * 8);
      vreg[j] = *(const short8*)(qkv + (long)(kv0 + tok) * QKVN + 2 * HID + head * HD + dc * 8);
    }
    __syncthreads();
    #pragma unroll
    for (int j = 0; j < 4; ++j) {
      const int tok = tokv[j], dc = dchv[j];
      *(short8*)(Ksb + ((tok * 256 + dc * 16) ^ ((tok & 7) << 4))) = kreg[j];
      const int dg = dc >> 1, h = dc & 1, kg = tok >> 2, kr = tok & 3;
      const int pos = (kg & 8) | ((kg & 1) << 2) | ((kg >> 1) & 3);
      *(short8*)(Vsb + (dg * 16 + pos) * 128 + kr * 32 + h * 16) = vreg[j];
    }
    __syncthreads();

    f32x4 s[4];
    __builtin_amdgcn_s_setprio(1);
    #pragma unroll
    for (int ct = 0; ct < 4; ++ct) {
      f32x4 a = {};
      #pragma unroll
      for (int kt = 0; kt < 4; ++kt) {
        short8 kb = *(const short8*)(Ksb +
            ((((ct * 16 + lr) * 256) + kt * 64 + lg * 16) ^ ((lr & 7) << 4)));
        a = mfma_16x16x32(qf[kt], kb, a);
      }
      s[ct] = a;
    }
    __builtin_amdgcn_s_setprio(0);

    #pragma unroll
    for (int r = 0; r < 4; ++r) {
      float pm = fmaxf(fmaxf(s[0][r], s[1][r]), fmaxf(s[2][r], s[3][r]));
      #pragma unroll
      for (int mask = 1; mask <= 8; mask <<= 1) pm = fmaxf(pm, __shfl_xor(pm, mask));
      pm *= scale;
      const float mnew = fmaxf(mrun[r], pm);
      const float corr = __expf(mrun[r] - mnew);
      float psum = 0.0f;
      #pragma unroll
      for (int ct = 0; ct < 4; ++ct) {
        const float p = __expf(s[ct][r] * scale - mnew);
        psum += p;
        bf16 pb = __float2bfloat16(p);
        Ps[wid][(lg * 4 + r) * 72 + ct * 16 + lr] = *(unsigned short*)&pb;
      }
      #pragma unroll
      for (int mask = 1; mask <= 8; mask <<= 1) psum += __shfl_xor(psum, mask);
      lrun[r] = lrun[r] * corr + psum;
      mrun[r] = mnew;
      #pragma unroll
      for (int dt = 0; dt < 8; ++dt) oacc[dt][r] *= corr;
    }

    short8 pa[2];
    #pragma unroll
    for (int kt = 0; kt < 2; ++kt)
      pa[kt] = *(const short8*)&Ps[wid][lr * 72 + kt * 32 + lg * 8];

    lds_cchar* vb0 = (lds_cchar*)Vsb + lane * 8;
    __builtin_amdgcn_s_setprio(1);
    #pragma unroll
    for (int dt = 0; dt < 8; ++dt) {
      lds_cchar* pd = vb0 + dt * 2048;
      ull r0, r1, r2, r3;
      asm volatile("ds_read_b64_tr_b16 %0, %1 offset:0"    : "=v"(r0) : "v"(pd));
      asm volatile("ds_read_b64_tr_b16 %0, %1 offset:512"  : "=v"(r1) : "v"(pd));
      asm volatile("ds_read_b64_tr_b16 %0, %1 offset:1024" : "=v"(r2) : "v"(pd));
      asm volatile("ds_read_b64_tr_b16 %0, %1 offset:1536" : "=v"(r3) : "v"(pd));
      asm volatile("s_waitcnt lgkmcnt(0)" ::: "memory");
      __builtin_amdgcn_sched_barrier(0);
      short8 vb_0, vb_1;
      ((ull*)&vb_0)[0] = r0; ((ull*)&vb_0)[1] = r1;
      ((ull*)&vb_1)[0] = r2; ((ull*)&vb_1)[1] = r3;
      oacc[dt] = mfma_16x16x32(pa[0], vb_0, oacc[dt]);
      oacc[dt] = mfma_16x16x32(pa[1], vb_1, oacc[dt]);
    }
    __builtin_amdgcn_s_setprio(0);
  }

  #pragma unroll
  for (int r = 0; r < 4; ++r) {
    const float inv = 1.0f / lrun[r];
    const long tok = qrow0 + lg * 4 + r;
    #pragma unroll
    for (int dt = 0; dt < 8; ++dt)
      ctx[tok * HID + head * HD + dt * 16 + lr] = __float2bfloat16(oacc[dt][r] * inv);
  }
}

extern "C" void kernel_launch(void* const* d_in, const int* in_sizes, int n_in,
                              void* d_out, int out_size, void* d_ws, size_t ws_size,
                              hipStream_t stream) {
  (void)in_sizes; (void)n_in; (void)out_size; (void)ws_size;
  const float* x     = (const float*)d_in[0];
  const float* Wqkv  = (const float*)d_in[1];
  const float* bqkv  = (const float*)d_in[2];
  const float* Wproj = (const float*)d_in[3];
  const float* qw    = (const float*)d_in[4];
  const float* kw    = (const float*)d_in[5];

  char* ws = (char*)d_ws;                       // total 125,829,120 B used
  bf16* xb     = (bf16*)ws;                     // 2048x3072 bf16 (12.58 MB)
  bf16* WqkvT  = (bf16*)(ws + 12582912);        // 9216x3072 bf16 (56.62 MB)
  bf16* WprojT = (bf16*)(ws + 69206016);        // 3072x3072 bf16 (18.87 MB)
  bf16* qkv    = (bf16*)(ws + 88080384);        // 2048x9216 bf16 (37.75 MB)
  bf16* ctx    = xb;                            // xb dead after GEMM1 -> reuse for ctx

  cvt_f32_bf16_vec<<<(SEQ * HID / 4 + 255) / 256, 256, 0, stream>>>(x, xb, SEQ * HID / 4);
  transpose_cvt<<<dim3(QKVN / 32, HID / 32), 256, 0, stream>>>(Wqkv, WqkvT, HID, QKVN);
  transpose_cvt<<<dim3(HID / 32, HID / 32), 256, 0, stream>>>(Wproj, WprojT, HID, HID);

  // GEMM1: M=2048 (8 tiles), N=9216 (72 tiles) -> 576 blocks (%8==0)
  gemm_pipe<1, 0><<<576, 512, 0, stream>>>(xb, WqkvT, bqkv, (void*)qkv,
                                           SEQ, QKVN, HID, QKVN / 128);

  rmsnorm_qk<<<SEQ * 48 / 4, 256, 0, stream>>>(qkv, qw, kw);

  attn_kernel<<<dim3(SEQ / 64, NH), 256, 0, stream>>>(qkv, ctx);

  // GEMM2: M=2048 (8), N=3072 (24) -> 192 blocks (%8==0)
  gemm_pipe<0, 1><<<192, 512, 0, stream>>>(ctx, WprojT, nullptr, d_out,
                                           SEQ, HID, HID, HID / 128);
}